// Round 10
// baseline (2736.387 us; speedup 1.0000x reference)
//
#include <hip/hip_runtime.h>
#include <cstdint>
#include <cstddef>

#define A_N 100000
#define B_N 200000
#define M_N 20000
#define POOL_N 220000   // M_N + B_N
#define HD 256
#define MAX_NB 10
#define N_MOLS 2000
#define ATOM_FDIM 35
#define FB_DIM 40

typedef unsigned short u16;
typedef __attribute__((ext_vector_type(8))) short bf16x8;
typedef __attribute__((ext_vector_type(4))) float f32x4;

// Static device buffers (BSS).
__device__ u16 g_msg0[(size_t)B_N * HD];      // bf16 messages (ping)
__device__ u16 g_msg1[(size_t)B_N * HD];      // bf16 messages (pong)
__device__ u16 g_tmsgh[(size_t)M_N * HD];     // bf16 tree messages
__device__ u16 g_P[(size_t)POOL_N * HD];      // P = pool @ W_h   (bf16)
__device__ u16 g_Q[(size_t)POOL_N * HD];      // Q = pool @ Wo[35:291] (bf16)
__device__ u16 g_binH[(size_t)B_N * HD];      // bf16 binput
__device__ u16 g_Fh[(size_t)A_N * HD];        // bf16 fatoms@Wo_top + bias
// packed split-bf16 weights in MFMA A-fragment order: [(c*16+t)*64+lane]*8+j
__device__ u16 g_pWh_hi[65536], g_pWh_lo[65536];
__device__ u16 g_pWo_hi[65536], g_pWo_lo[65536];
__device__ int g_mstart[N_MOLS + 1];          // molecule atom-range starts

__device__ __forceinline__ u16 f2b(float f)
{
    union { float f; unsigned u; } x; x.f = f;
    const unsigned r = x.u + 0x7FFFu + ((x.u >> 16) & 1u);
    return (u16)(r >> 16);
}
__device__ __forceinline__ float b2f(u16 h) { return __uint_as_float((unsigned)h << 16); }
__device__ __forceinline__ float blo(unsigned u) { return __uint_as_float(u << 16); }
__device__ __forceinline__ float bhi(unsigned u) { return __uint_as_float(u & 0xffff0000u); }

__device__ __forceinline__ int lbound(const int* __restrict__ s, int n, int v)
{
    int l = 0, r = n;
    while (l < r) { const int mid = (l + r) >> 1; if (s[mid] < v) l = mid + 1; else r = mid; }
    return l;
}

// async global->LDS, 16 B per lane (LDS dest must be wave-uniform base + lane*16).
__device__ __forceinline__ void gl_lds16(const u16* g, u16* l)
{
    __builtin_amdgcn_global_load_lds(
        (const __attribute__((address_space(1))) unsigned int*)g,
        (__attribute__((address_space(3))) unsigned int*)l,
        16, 0, 0);
}

// ---------------- K0: fused setup ----------------
// Segments by blockIdx: [0,5000) cvt tmsg->bf16; [5000,5032) packW;
// [5032,5040) mstart (binary search on sorted scope; 2001 entries).
__global__ __launch_bounds__(256)
void k_setup(const float* __restrict__ tmsg,
             const float* __restrict__ Wh, const float* __restrict__ Wo,
             const int* __restrict__ scope)
{
    const int bid = blockIdx.x;
    const int tid = threadIdx.x;
    if (bid < 5000) {                       // cvt tree messages to bf16
        const int i = (bid * 256 + tid) * 4;
        if (i < M_N * HD) {
            const float4 v = *(const float4*)(tmsg + i);
            ushort4 o;
            o.x = f2b(v.x); o.y = f2b(v.y); o.z = f2b(v.z); o.w = f2b(v.w);
            *(ushort4*)(g_tmsgh + i) = o;
        }
    } else if (bid < 5032) {                // packW: split-bf16 MFMA fragments
        const int id = (bid - 5000) * 256 + tid;   // 0..8191
        const int l = id & 63;
        const int t = (id >> 6) & 15;
        const int c = id >> 10;
        const int n = t * 16 + (l & 15);
        const int kb = c * 32 + ((l >> 4) << 3);
        const size_t base = (size_t)id * 8;
        #pragma unroll
        for (int j = 0; j < 8; ++j) {
            const int k = kb + j;
            const float wh = Wh[(size_t)k * HD + n];
            const u16 hh = f2b(wh);
            g_pWh_hi[base + j] = hh;
            g_pWh_lo[base + j] = f2b(wh - b2f(hh));
            const float wo = Wo[(size_t)(35 + k) * HD + n];
            const u16 oh = f2b(wo);
            g_pWo_hi[base + j] = oh;
            g_pWo_lo[base + j] = f2b(wo - b2f(oh));
        }
    } else {                                // mstart via binary search (scope sorted)
        const int m = (bid - 5032) * 256 + tid;
        if (m <= N_MOLS) g_mstart[m] = lbound(scope, A_N, m);
    }
}

// ---- K1 (merged): blocks [0,512) = binH/msg0 from fbonds@Wi (R15 structure);
//                   blocks [512,1024) = Fh from fatoms@Wo[0:35]+bias.
// R20: both paths are latency-bound at 2 blocks/CU (R15: k_in occupancy 20%,
// VALUBusy 32%) — co-residency in ONE dispatch lets each fill the other's idle
// issue slots, and saves a launch gap. Grids are the R15-measured 512 each.
__global__ __launch_bounds__(256, 2)
void k_inF(const float* __restrict__ fbonds, const float* __restrict__ Wi,
           const float* __restrict__ fatoms, const float* __restrict__ Wo,
           const float* __restrict__ bias)
{
    const int lane = threadIdx.x & 63;
    if (blockIdx.x < 512) {
        const int wid  = (blockIdx.x * 256 + threadIdx.x) >> 6;
        const int nw   = (512 * 256) >> 6;

        float4 w[FB_DIM];                              // W_i[:, lane*4..+4)
        #pragma unroll
        for (int k = 0; k < FB_DIM; ++k)
            w[k] = *(const float4*)&Wi[(size_t)k * HD + lane * 4];

        #pragma unroll 1
        for (int row = wid; row < B_N; row += nw) {
            const float* fr = fbonds + (size_t)row * FB_DIM;
            float ax = 0.f, ay = 0.f, az = 0.f, aw = 0.f;
            #pragma unroll
            for (int q = 0; q < FB_DIM / 4; ++q) {
                const float4 fv = *(const float4*)(fr + q * 4);
                ax += fv.x * w[q*4+0].x; ay += fv.x * w[q*4+0].y;
                az += fv.x * w[q*4+0].z; aw += fv.x * w[q*4+0].w;
                ax += fv.y * w[q*4+1].x; ay += fv.y * w[q*4+1].y;
                az += fv.y * w[q*4+1].z; aw += fv.y * w[q*4+1].w;
                ax += fv.z * w[q*4+2].x; ay += fv.z * w[q*4+2].y;
                az += fv.z * w[q*4+2].z; aw += fv.z * w[q*4+2].w;
                ax += fv.w * w[q*4+3].x; ay += fv.w * w[q*4+3].y;
                az += fv.w * w[q*4+3].z; aw += fv.w * w[q*4+3].w;
            }
            const size_t base = (size_t)row * HD + lane * 4;
            ushort4 bi;
            bi.x = f2b(ax); bi.y = f2b(ay); bi.z = f2b(az); bi.w = f2b(aw);
            *(ushort4*)(g_binH + base) = bi;
            ushort4 o;
            o.x = f2b(fmaxf(ax, 0.f)); o.y = f2b(fmaxf(ay, 0.f));
            o.z = f2b(fmaxf(az, 0.f)); o.w = f2b(fmaxf(aw, 0.f));
            *(ushort4*)(g_msg0 + base) = o;
        }
    } else {
        const int wid  = ((blockIdx.x - 512) * 256 + threadIdx.x) >> 6;
        const int nw   = (512 * 256) >> 6;

        float4 w[ATOM_FDIM];
        #pragma unroll
        for (int k = 0; k < ATOM_FDIM; ++k)
            w[k] = *(const float4*)&Wo[(size_t)k * HD + lane * 4];
        const float4 b4 = *(const float4*)&bias[lane * 4];

        #pragma unroll 1
        for (int row = wid; row < A_N; row += nw) {
            const float* fr = fatoms + (size_t)row * ATOM_FDIM;
            float ax = b4.x, ay = b4.y, az = b4.z, aw = b4.w;
            #pragma unroll
            for (int k = 0; k < ATOM_FDIM; ++k) {
                const float f = fr[k];
                ax += f * w[k].x; ay += f * w[k].y;
                az += f * w[k].z; aw += f * w[k].w;
            }
            ushort4 o;
            o.x = f2b(ax); o.y = f2b(ay); o.z = f2b(az); o.w = f2b(aw);
            *(ushort4*)(g_Fh + (size_t)row * HD + lane * 4) = o;
        }
    }
}

// ------- K2: MFMA GEMM — dst[row] = bf16(pool[row] @ W) with split-bf16 W -------
// R15: LDS-staged weights (async global_load_lds, double-buffered, one
// __syncthreads per c-step). Barrier vmcnt-drain = buffer-ready guarantee.
__global__ __launch_bounds__(256, 2)
void k_gemmMF(int sel, int rowStart, int rowEnd)
{
    const u16* msrc = (sel == 1) ? g_msg1 : g_msg0;
    const u16* pHi  = (sel == 2) ? g_pWo_hi : g_pWh_hi;
    const u16* pLo  = (sel == 2) ? g_pWo_lo : g_pWh_lo;
    u16* dst        = (sel == 2) ? g_Q : g_P;

    __shared__ u16 lds[2][16384];         // 64 KB: [buf][hi 8192 | lo 8192]

    const int tid  = threadIdx.x;
    const int lane = tid & 63;
    const int wv   = tid >> 6;            // 0..3
    const int l15  = lane & 15;
    const int quad = lane >> 4;
    const int tOff = (wv & 1) * 8;        // col-half: tiles [tOff, tOff+8)

    int rowIdeal[4];
    const u16* srow[4];
    #pragma unroll
    for (int rg = 0; rg < 4; ++rg) {
        const int ri = rowStart + blockIdx.x * 128 + (wv >> 1) * 64 + rg * 16 + l15;
        rowIdeal[rg] = ri;
        const int r = (ri < rowEnd) ? ri : (rowEnd - 1);
        srow[rg] = (r < M_N) ? (g_tmsgh + (size_t)r * HD)
                             : (msrc + (size_t)(r - M_N) * HD);
    }

    #define STAGE(bf, cc) do {                                            \
        const u16* sh_ = pHi + (cc) * 8192 + tid * 8;                     \
        const u16* sl_ = pLo + (cc) * 8192 + tid * 8;                     \
        u16* dh_ = &lds[bf][tid * 8];                                     \
        u16* dl_ = &lds[bf][8192 + tid * 8];                              \
        gl_lds16(sh_,        dh_);                                        \
        gl_lds16(sh_ + 2048, dh_ + 2048);                                 \
        gl_lds16(sh_ + 4096, dh_ + 4096);                                 \
        gl_lds16(sh_ + 6144, dh_ + 6144);                                 \
        gl_lds16(sl_,        dl_);                                        \
        gl_lds16(sl_ + 2048, dl_ + 2048);                                 \
        gl_lds16(sl_ + 4096, dl_ + 4096);                                 \
        gl_lds16(sl_ + 6144, dl_ + 6144);                                 \
    } while (0)

    f32x4 acc[4][8];
    #pragma unroll
    for (int rg = 0; rg < 4; ++rg)
        #pragma unroll
        for (int t = 0; t < 8; ++t)
            acc[rg][t] = (f32x4){0.f, 0.f, 0.f, 0.f};

    STAGE(0, 0);
    bf16x8 b0 = *(const bf16x8*)(srow[0] + quad * 8);
    bf16x8 b1 = *(const bf16x8*)(srow[1] + quad * 8);
    bf16x8 b2 = *(const bf16x8*)(srow[2] + quad * 8);
    bf16x8 b3 = *(const bf16x8*)(srow[3] + quad * 8);

    #pragma unroll 1
    for (int c = 0; c < 8; ++c) {
        __syncthreads();                   // buf[c&1] staged + prev buf free
        if (c < 7) STAGE((c + 1) & 1, c + 1);

        const int cn = (c + 1) & 7;        // B-row prefetch (wrap re-reads c=0)
        const bf16x8 n0 = *(const bf16x8*)(srow[0] + cn * 32 + quad * 8);
        const bf16x8 n1 = *(const bf16x8*)(srow[1] + cn * 32 + quad * 8);
        const bf16x8 n2 = *(const bf16x8*)(srow[2] + cn * 32 + quad * 8);
        const bf16x8 n3 = *(const bf16x8*)(srow[3] + cn * 32 + quad * 8);

        const u16* Lh = &lds[c & 1][(size_t)tOff * 512 + lane * 8];
        const u16* Ll = Lh + 8192;
        #pragma unroll
        for (int t = 0; t < 8; ++t) {
            const bf16x8 ah = *(const bf16x8*)(Lh + t * 512);
            acc[0][t] = __builtin_amdgcn_mfma_f32_16x16x32_bf16(ah, b0, acc[0][t], 0, 0, 0);
            acc[1][t] = __builtin_amdgcn_mfma_f32_16x16x32_bf16(ah, b1, acc[1][t], 0, 0, 0);
            acc[2][t] = __builtin_amdgcn_mfma_f32_16x16x32_bf16(ah, b2, acc[2][t], 0, 0, 0);
            acc[3][t] = __builtin_amdgcn_mfma_f32_16x16x32_bf16(ah, b3, acc[3][t], 0, 0, 0);
            const bf16x8 al = *(const bf16x8*)(Ll + t * 512);
            acc[0][t] = __builtin_amdgcn_mfma_f32_16x16x32_bf16(al, b0, acc[0][t], 0, 0, 0);
            acc[1][t] = __builtin_amdgcn_mfma_f32_16x16x32_bf16(al, b1, acc[1][t], 0, 0, 0);
            acc[2][t] = __builtin_amdgcn_mfma_f32_16x16x32_bf16(al, b2, acc[2][t], 0, 0, 0);
            acc[3][t] = __builtin_amdgcn_mfma_f32_16x16x32_bf16(al, b3, acc[3][t], 0, 0, 0);
        }
        b0 = n0; b1 = n1; b2 = n2; b3 = n3;
    }
    #undef STAGE

    #pragma unroll
    for (int rg = 0; rg < 4; ++rg) {
        if (rowIdeal[rg] < rowEnd) {
            u16* drow = dst + (size_t)rowIdeal[rg] * HD + tOff * 16 + quad * 4;
            #pragma unroll
            for (int t = 0; t < 8; ++t) {
                ushort4 o;
                o.x = f2b(acc[rg][t][0]); o.y = f2b(acc[rg][t][1]);
                o.z = f2b(acc[rg][t][2]); o.w = f2b(acc[rg][t][3]);
                *(ushort4*)(drow + t * 16) = o;
            }
        }
    }
}

// ------- K3: dst = bf16(relu(binH + sum_j P[bgraph[r][j]])) — pure gather -------
// R20: back to one full dispatch (diagnostic quartering done; saves launch gaps).
__global__ __launch_bounds__(256)
void k_gather(const int* __restrict__ bgraph, int dstSel)
{
    u16* dst = dstSel ? g_msg1 : g_msg0;
    __shared__ int idx_s[8][MAX_NB];
    const int tid = threadIdx.x;
    const int rowBase = blockIdx.x * 8;
    if (tid < 8 * MAX_NB) {
        const int r = tid / MAX_NB;
        const int j = tid - r * MAX_NB;
        idx_s[r][j] = bgraph[(size_t)(rowBase + r) * MAX_NB + j];
    }
    __syncthreads();
    const int rl = tid >> 5;           // [0,8)
    const int c  = (tid & 31) << 3;    // 8 bf16 = 16 B per thread
    const int row = rowBase + rl;

    const uint4 bv = *(const uint4*)(g_binH + (size_t)row * HD + c);
    float s[8] = {0.f,0.f,0.f,0.f,0.f,0.f,0.f,0.f};
    #pragma unroll
    for (int j = 0; j < MAX_NB; ++j) {
        const uint4 v = *(const uint4*)(g_P + (size_t)idx_s[rl][j] * HD + c);
        s[0] += blo(v.x); s[1] += bhi(v.x);
        s[2] += blo(v.y); s[3] += bhi(v.y);
        s[4] += blo(v.z); s[5] += bhi(v.z);
        s[6] += blo(v.w); s[7] += bhi(v.w);
    }
    uint4 w;
    w.x = ((unsigned)f2b(fmaxf(s[0] + blo(bv.x), 0.f)))
        | ((unsigned)f2b(fmaxf(s[1] + bhi(bv.x), 0.f)) << 16);
    w.y = ((unsigned)f2b(fmaxf(s[2] + blo(bv.y), 0.f)))
        | ((unsigned)f2b(fmaxf(s[3] + bhi(bv.y), 0.f)) << 16);
    w.z = ((unsigned)f2b(fmaxf(s[4] + blo(bv.z), 0.f)))
        | ((unsigned)f2b(fmaxf(s[5] + bhi(bv.z), 0.f)) << 16);
    w.w = ((unsigned)f2b(fmaxf(s[6] + blo(bv.w), 0.f)))
        | ((unsigned)f2b(fmaxf(s[7] + bhi(bv.w), 0.f)) << 16);
    *(uint4*)(dst + (size_t)row * HD + c) = w;
}

// ------- K5: out[mol] = mean_a relu(Fh[a] + sum_j Q[agraph[a][j]]) -------
// R20: R19 counters (FETCH 525 MB ~= zero-reuse bound; was 334 MB at R14)
// proved the quarter-col split killed L2 row reuse. New shape: ONE block per
// molecule, 512 threads; 32 threads own a FULL 512B Q-row per atom (16 atom
// groups, stride 16) -> one fetch per gathered row, max line utilization.
// LDS reduce (padded [16][260]); direct mean store; no atomics.
__global__ __launch_bounds__(512)
void k_gatherA(const int* __restrict__ agraph, float* __restrict__ out)
{
    const int mol = blockIdx.x;
    const int tid = threadIdx.x;                 // 0..511
    const int grp = tid >> 5;                    // 16 groups of 32 threads
    const int lc  = (tid & 31) * 8;              // col [0,256)

    const int s0 = g_mstart[mol];
    const int s1 = g_mstart[mol + 1];

    float s[8] = {0.f,0.f,0.f,0.f,0.f,0.f,0.f,0.f};
    #pragma unroll 1
    for (int a = s0 + grp; a < s1; a += 16) {
        const int* ap = agraph + (size_t)a * MAX_NB;
        int idx[MAX_NB];
        #pragma unroll
        for (int j = 0; j < MAX_NB; ++j) idx[j] = ap[j];
        const uint4 fv = *(const uint4*)(g_Fh + (size_t)a * HD + lc);
        float g0=0.f,g1=0.f,g2=0.f,g3=0.f,g4=0.f,g5=0.f,g6=0.f,g7=0.f;
        #pragma unroll
        for (int j = 0; j < MAX_NB; ++j) {
            const uint4 v = *(const uint4*)(g_Q + (size_t)idx[j] * HD + lc);
            g0 += blo(v.x); g1 += bhi(v.x);
            g2 += blo(v.y); g3 += bhi(v.y);
            g4 += blo(v.z); g5 += bhi(v.z);
            g6 += blo(v.w); g7 += bhi(v.w);
        }
        s[0] += fmaxf(g0 + blo(fv.x), 0.f); s[1] += fmaxf(g1 + bhi(fv.x), 0.f);
        s[2] += fmaxf(g2 + blo(fv.y), 0.f); s[3] += fmaxf(g3 + bhi(fv.y), 0.f);
        s[4] += fmaxf(g4 + blo(fv.z), 0.f); s[5] += fmaxf(g5 + bhi(fv.z), 0.f);
        s[6] += fmaxf(g6 + blo(fv.w), 0.f); s[7] += fmaxf(g7 + bhi(fv.w), 0.f);
    }

    __shared__ float red[16][260];               // padded: ~16.6 KB
    #pragma unroll
    for (int q = 0; q < 8; ++q) red[grp][lc + q] = s[q];
    __syncthreads();
    if (tid < 256) {
        float acc = 0.f;
        #pragma unroll
        for (int g = 0; g < 16; ++g) acc += red[g][tid];
        const float inv = 1.0f / fmaxf((float)(s1 - s0), 1.0f);
        out[(size_t)mol * HD + tid] = acc * inv;
    }
}

// ---------------- launch ----------------
extern "C" void kernel_launch(void* const* d_in, const int* in_sizes, int n_in,
                              void* d_out, int out_size, void* d_ws, size_t ws_size,
                              hipStream_t stream)
{
    const float* fatoms = (const float*)d_in[0];
    const float* fbonds = (const float*)d_in[1];
    const int*   agraph = (const int*)d_in[2];
    const int*   bgraph = (const int*)d_in[3];
    const float* tmsg   = (const float*)d_in[4];
    const int*   scope  = (const int*)d_in[5];
    const float* W_i    = (const float*)d_in[6];
    const float* W_h    = (const float*)d_in[7];
    const float* W_o    = (const float*)d_in[8];
    const float* W_ob   = (const float*)d_in[9];
    float* out = (float*)d_out;

    (void)d_ws; (void)ws_size;

    k_setup<<<5040, 256, 0, stream>>>(tmsg, W_h, W_o, scope);
    k_inF<<<1024, 256, 0, stream>>>(fbonds, W_i, fatoms, W_o, W_ob);  // binH+msg0 | Fh

    // iter 0: P = [tmsg; msg0] @ Wh; msg1 = relu(binH + gatherP)
    k_gemmMF<<<(POOL_N + 127) / 128, 256, 0, stream>>>(0, 0, POOL_N);
    k_gather<<<B_N / 8, 256, 0, stream>>>(bgraph, 1);
    // iter 1: only msg rows of P change
    k_gemmMF<<<(B_N + 127) / 128, 256, 0, stream>>>(1, M_N, POOL_N);
    k_gather<<<B_N / 8, 256, 0, stream>>>(bgraph, 0);

    // readout: Q = [tmsg; msg0] @ Wo[35:291]; gather+mean
    k_gemmMF<<<(POOL_N + 127) / 128, 256, 0, stream>>>(2, 0, POOL_N);
    k_gatherA<<<N_MOLS, 512, 0, stream>>>(agraph, out);
}

// Round 11
// 1072.456 us; speedup vs baseline: 2.5515x; 2.5515x over previous
//
#include <hip/hip_runtime.h>
#include <cstdint>
#include <cstddef>

#define A_N 100000
#define B_N 200000
#define M_N 20000
#define POOL_N 220000   // M_N + B_N
#define HD 256
#define MAX_NB 10
#define N_MOLS 2000
#define ATOM_FDIM 35
#define FB_DIM 40

typedef unsigned short u16;
typedef __attribute__((ext_vector_type(8))) short bf16x8;
typedef __attribute__((ext_vector_type(4))) float f32x4;

// Static device buffers (BSS).
__device__ u16 g_msg0[(size_t)B_N * HD];      // bf16 messages (ping)
__device__ u16 g_msg1[(size_t)B_N * HD];      // bf16 messages (pong)
__device__ u16 g_tmsgh[(size_t)M_N * HD];     // bf16 tree messages
__device__ u16 g_P[(size_t)POOL_N * HD];      // P = pool @ W_h   (bf16)
__device__ u16 g_Q[(size_t)POOL_N * HD];      // Q = pool @ Wo[35:291] (bf16)
__device__ u16 g_binH[(size_t)B_N * HD];      // bf16 binput
__device__ u16 g_Fh[(size_t)A_N * HD];        // bf16 fatoms@Wo_top + bias
// packed split-bf16 weights in MFMA A-fragment order: [(c*16+t)*64+lane]*8+j
__device__ u16 g_pWh_hi[65536], g_pWh_lo[65536];
__device__ u16 g_pWo_hi[65536], g_pWo_lo[65536];
__device__ int g_mstart[N_MOLS + 1];          // molecule atom-range starts

__device__ __forceinline__ u16 f2b(float f)
{
    union { float f; unsigned u; } x; x.f = f;
    const unsigned r = x.u + 0x7FFFu + ((x.u >> 16) & 1u);
    return (u16)(r >> 16);
}
__device__ __forceinline__ float b2f(u16 h) { return __uint_as_float((unsigned)h << 16); }
__device__ __forceinline__ float blo(unsigned u) { return __uint_as_float(u << 16); }
__device__ __forceinline__ float bhi(unsigned u) { return __uint_as_float(u & 0xffff0000u); }

__device__ __forceinline__ int lbound(const int* __restrict__ s, int n, int v)
{
    int l = 0, r = n;
    while (l < r) { const int mid = (l + r) >> 1; if (s[mid] < v) l = mid + 1; else r = mid; }
    return l;
}

// async global->LDS, 16 B per lane (LDS dest must be wave-uniform base + lane*16).
__device__ __forceinline__ void gl_lds16(const u16* g, u16* l)
{
    __builtin_amdgcn_global_load_lds(
        (const __attribute__((address_space(1))) unsigned int*)g,
        (__attribute__((address_space(3))) unsigned int*)l,
        16, 0, 0);
}

// ---------------- K0: fused setup ----------------
// Segments by blockIdx: [0,5000) cvt tmsg->bf16; [5000,5032) packW;
// [5032,5040) mstart (binary search on sorted scope; 2001 entries).
__global__ __launch_bounds__(256)
void k_setup(const float* __restrict__ tmsg,
             const float* __restrict__ Wh, const float* __restrict__ Wo,
             const int* __restrict__ scope)
{
    const int bid = blockIdx.x;
    const int tid = threadIdx.x;
    if (bid < 5000) {                       // cvt tree messages to bf16
        const int i = (bid * 256 + tid) * 4;
        if (i < M_N * HD) {
            const float4 v = *(const float4*)(tmsg + i);
            ushort4 o;
            o.x = f2b(v.x); o.y = f2b(v.y); o.z = f2b(v.z); o.w = f2b(v.w);
            *(ushort4*)(g_tmsgh + i) = o;
        }
    } else if (bid < 5032) {                // packW: split-bf16 MFMA fragments
        const int id = (bid - 5000) * 256 + tid;   // 0..8191
        const int l = id & 63;
        const int t = (id >> 6) & 15;
        const int c = id >> 10;
        const int n = t * 16 + (l & 15);
        const int kb = c * 32 + ((l >> 4) << 3);
        const size_t base = (size_t)id * 8;
        #pragma unroll
        for (int j = 0; j < 8; ++j) {
            const int k = kb + j;
            const float wh = Wh[(size_t)k * HD + n];
            const u16 hh = f2b(wh);
            g_pWh_hi[base + j] = hh;
            g_pWh_lo[base + j] = f2b(wh - b2f(hh));
            const float wo = Wo[(size_t)(35 + k) * HD + n];
            const u16 oh = f2b(wo);
            g_pWo_hi[base + j] = oh;
            g_pWo_lo[base + j] = f2b(wo - b2f(oh));
        }
    } else {                                // mstart via binary search (scope sorted)
        const int m = (bid - 5032) * 256 + tid;
        if (m <= N_MOLS) g_mstart[m] = lbound(scope, A_N, m);
    }
}

// ---------------- K1: binH = bf16(fbonds @ W_i); msg0 = bf16(relu(binput)) ----------------
// R21: exact R15-measured structure (122 us; VGPR 120, grid 512, (256,2)).
// R16/R18/R20 all proved alternatives regress: tighter caps or merged branches
// make the compiler sink the weight array (re-load per row, up to 3.1 GB HBM).
// DO NOT merge this kernel with anything or change its launch bounds.
__global__ __launch_bounds__(256, 2)
void k_in(const float* __restrict__ fbonds, const float* __restrict__ Wi)
{
    const int lane = threadIdx.x & 63;
    const int wid  = (blockIdx.x * 256 + threadIdx.x) >> 6;
    const int nw   = (gridDim.x * 256) >> 6;

    float4 w[FB_DIM];                                  // W_i[:, lane*4..+4)
    #pragma unroll
    for (int k = 0; k < FB_DIM; ++k)
        w[k] = *(const float4*)&Wi[(size_t)k * HD + lane * 4];

    #pragma unroll 1
    for (int row = wid; row < B_N; row += nw) {
        const float* fr = fbonds + (size_t)row * FB_DIM;
        float ax = 0.f, ay = 0.f, az = 0.f, aw = 0.f;
        #pragma unroll
        for (int q = 0; q < FB_DIM / 4; ++q) {
            const float4 fv = *(const float4*)(fr + q * 4);
            ax += fv.x * w[q*4+0].x; ay += fv.x * w[q*4+0].y;
            az += fv.x * w[q*4+0].z; aw += fv.x * w[q*4+0].w;
            ax += fv.y * w[q*4+1].x; ay += fv.y * w[q*4+1].y;
            az += fv.y * w[q*4+1].z; aw += fv.y * w[q*4+1].w;
            ax += fv.z * w[q*4+2].x; ay += fv.z * w[q*4+2].y;
            az += fv.z * w[q*4+2].z; aw += fv.z * w[q*4+2].w;
            ax += fv.w * w[q*4+3].x; ay += fv.w * w[q*4+3].y;
            az += fv.w * w[q*4+3].z; aw += fv.w * w[q*4+3].w;
        }
        const size_t base = (size_t)row * HD + lane * 4;
        ushort4 bi;
        bi.x = f2b(ax); bi.y = f2b(ay); bi.z = f2b(az); bi.w = f2b(aw);
        *(ushort4*)(g_binH + base) = bi;
        ushort4 o;
        o.x = f2b(fmaxf(ax, 0.f)); o.y = f2b(fmaxf(ay, 0.f));
        o.z = f2b(fmaxf(az, 0.f)); o.w = f2b(fmaxf(aw, 0.f));
        *(ushort4*)(g_msg0 + base) = o;
    }
}

// ------- K2: MFMA GEMM — dst[row] = bf16(pool[row] @ W) with split-bf16 W -------
// R15: LDS-staged weights (async global_load_lds, double-buffered, one
// __syncthreads per c-step). Barrier vmcnt-drain = buffer-ready guarantee.
__global__ __launch_bounds__(256, 2)
void k_gemmMF(int sel, int rowStart, int rowEnd)
{
    const u16* msrc = (sel == 1) ? g_msg1 : g_msg0;
    const u16* pHi  = (sel == 2) ? g_pWo_hi : g_pWh_hi;
    const u16* pLo  = (sel == 2) ? g_pWo_lo : g_pWh_lo;
    u16* dst        = (sel == 2) ? g_Q : g_P;

    __shared__ u16 lds[2][16384];         // 64 KB: [buf][hi 8192 | lo 8192]

    const int tid  = threadIdx.x;
    const int lane = tid & 63;
    const int wv   = tid >> 6;            // 0..3
    const int l15  = lane & 15;
    const int quad = lane >> 4;
    const int tOff = (wv & 1) * 8;        // col-half: tiles [tOff, tOff+8)

    int rowIdeal[4];
    const u16* srow[4];
    #pragma unroll
    for (int rg = 0; rg < 4; ++rg) {
        const int ri = rowStart + blockIdx.x * 128 + (wv >> 1) * 64 + rg * 16 + l15;
        rowIdeal[rg] = ri;
        const int r = (ri < rowEnd) ? ri : (rowEnd - 1);
        srow[rg] = (r < M_N) ? (g_tmsgh + (size_t)r * HD)
                             : (msrc + (size_t)(r - M_N) * HD);
    }

    #define STAGE(bf, cc) do {                                            \
        const u16* sh_ = pHi + (cc) * 8192 + tid * 8;                     \
        const u16* sl_ = pLo + (cc) * 8192 + tid * 8;                     \
        u16* dh_ = &lds[bf][tid * 8];                                     \
        u16* dl_ = &lds[bf][8192 + tid * 8];                              \
        gl_lds16(sh_,        dh_);                                        \
        gl_lds16(sh_ + 2048, dh_ + 2048);                                 \
        gl_lds16(sh_ + 4096, dh_ + 4096);                                 \
        gl_lds16(sh_ + 6144, dh_ + 6144);                                 \
        gl_lds16(sl_,        dl_);                                        \
        gl_lds16(sl_ + 2048, dl_ + 2048);                                 \
        gl_lds16(sl_ + 4096, dl_ + 4096);                                 \
        gl_lds16(sl_ + 6144, dl_ + 6144);                                 \
    } while (0)

    f32x4 acc[4][8];
    #pragma unroll
    for (int rg = 0; rg < 4; ++rg)
        #pragma unroll
        for (int t = 0; t < 8; ++t)
            acc[rg][t] = (f32x4){0.f, 0.f, 0.f, 0.f};

    STAGE(0, 0);
    bf16x8 b0 = *(const bf16x8*)(srow[0] + quad * 8);
    bf16x8 b1 = *(const bf16x8*)(srow[1] + quad * 8);
    bf16x8 b2 = *(const bf16x8*)(srow[2] + quad * 8);
    bf16x8 b3 = *(const bf16x8*)(srow[3] + quad * 8);

    #pragma unroll 1
    for (int c = 0; c < 8; ++c) {
        __syncthreads();                   // buf[c&1] staged + prev buf free
        if (c < 7) STAGE((c + 1) & 1, c + 1);

        const int cn = (c + 1) & 7;        // B-row prefetch (wrap re-reads c=0)
        const bf16x8 n0 = *(const bf16x8*)(srow[0] + cn * 32 + quad * 8);
        const bf16x8 n1 = *(const bf16x8*)(srow[1] + cn * 32 + quad * 8);
        const bf16x8 n2 = *(const bf16x8*)(srow[2] + cn * 32 + quad * 8);
        const bf16x8 n3 = *(const bf16x8*)(srow[3] + cn * 32 + quad * 8);

        const u16* Lh = &lds[c & 1][(size_t)tOff * 512 + lane * 8];
        const u16* Ll = Lh + 8192;
        #pragma unroll
        for (int t = 0; t < 8; ++t) {
            const bf16x8 ah = *(const bf16x8*)(Lh + t * 512);
            acc[0][t] = __builtin_amdgcn_mfma_f32_16x16x32_bf16(ah, b0, acc[0][t], 0, 0, 0);
            acc[1][t] = __builtin_amdgcn_mfma_f32_16x16x32_bf16(ah, b1, acc[1][t], 0, 0, 0);
            acc[2][t] = __builtin_amdgcn_mfma_f32_16x16x32_bf16(ah, b2, acc[2][t], 0, 0, 0);
            acc[3][t] = __builtin_amdgcn_mfma_f32_16x16x32_bf16(ah, b3, acc[3][t], 0, 0, 0);
            const bf16x8 al = *(const bf16x8*)(Ll + t * 512);
            acc[0][t] = __builtin_amdgcn_mfma_f32_16x16x32_bf16(al, b0, acc[0][t], 0, 0, 0);
            acc[1][t] = __builtin_amdgcn_mfma_f32_16x16x32_bf16(al, b1, acc[1][t], 0, 0, 0);
            acc[2][t] = __builtin_amdgcn_mfma_f32_16x16x32_bf16(al, b2, acc[2][t], 0, 0, 0);
            acc[3][t] = __builtin_amdgcn_mfma_f32_16x16x32_bf16(al, b3, acc[3][t], 0, 0, 0);
        }
        b0 = n0; b1 = n1; b2 = n2; b3 = n3;
    }
    #undef STAGE

    #pragma unroll
    for (int rg = 0; rg < 4; ++rg) {
        if (rowIdeal[rg] < rowEnd) {
            u16* drow = dst + (size_t)rowIdeal[rg] * HD + tOff * 16 + quad * 4;
            #pragma unroll
            for (int t = 0; t < 8; ++t) {
                ushort4 o;
                o.x = f2b(acc[rg][t][0]); o.y = f2b(acc[rg][t][1]);
                o.z = f2b(acc[rg][t][2]); o.w = f2b(acc[rg][t][3]);
                *(ushort4*)(drow + t * 16) = o;
            }
        }
    }
}

// ------- K3: dst = bf16(relu(binH + sum_j P[bgraph[r][j]])) — pure gather -------
__global__ __launch_bounds__(256)
void k_gather(const int* __restrict__ bgraph, int dstSel)
{
    u16* dst = dstSel ? g_msg1 : g_msg0;
    __shared__ int idx_s[8][MAX_NB];
    const int tid = threadIdx.x;
    const int rowBase = blockIdx.x * 8;
    if (tid < 8 * MAX_NB) {
        const int r = tid / MAX_NB;
        const int j = tid - r * MAX_NB;
        idx_s[r][j] = bgraph[(size_t)(rowBase + r) * MAX_NB + j];
    }
    __syncthreads();
    const int rl = tid >> 5;           // [0,8)
    const int c  = (tid & 31) << 3;    // 8 bf16 = 16 B per thread
    const int row = rowBase + rl;

    const uint4 bv = *(const uint4*)(g_binH + (size_t)row * HD + c);
    float s[8] = {0.f,0.f,0.f,0.f,0.f,0.f,0.f,0.f};
    #pragma unroll
    for (int j = 0; j < MAX_NB; ++j) {
        const uint4 v = *(const uint4*)(g_P + (size_t)idx_s[rl][j] * HD + c);
        s[0] += blo(v.x); s[1] += bhi(v.x);
        s[2] += blo(v.y); s[3] += bhi(v.y);
        s[4] += blo(v.z); s[5] += bhi(v.z);
        s[6] += blo(v.w); s[7] += bhi(v.w);
    }
    uint4 w;
    w.x = ((unsigned)f2b(fmaxf(s[0] + blo(bv.x), 0.f)))
        | ((unsigned)f2b(fmaxf(s[1] + bhi(bv.x), 0.f)) << 16);
    w.y = ((unsigned)f2b(fmaxf(s[2] + blo(bv.y), 0.f)))
        | ((unsigned)f2b(fmaxf(s[3] + bhi(bv.y), 0.f)) << 16);
    w.z = ((unsigned)f2b(fmaxf(s[4] + blo(bv.z), 0.f)))
        | ((unsigned)f2b(fmaxf(s[5] + bhi(bv.z), 0.f)) << 16);
    w.w = ((unsigned)f2b(fmaxf(s[6] + blo(bv.w), 0.f)))
        | ((unsigned)f2b(fmaxf(s[7] + bhi(bv.w), 0.f)) << 16);
    *(uint4*)(dst + (size_t)row * HD + c) = w;
}

// ------- K4: Fh = bf16(fatoms @ Wo[0:35] + bias) -------
// R21: exact R15-measured structure (separate kernel; see k_in note).
__global__ __launch_bounds__(256, 2)
void k_F(const float* __restrict__ fatoms, const float* __restrict__ Wo,
         const float* __restrict__ bias)
{
    const int lane = threadIdx.x & 63;
    const int wid  = (blockIdx.x * 256 + threadIdx.x) >> 6;
    const int nw   = (gridDim.x * 256) >> 6;

    float4 w[ATOM_FDIM];
    #pragma unroll
    for (int k = 0; k < ATOM_FDIM; ++k)
        w[k] = *(const float4*)&Wo[(size_t)k * HD + lane * 4];
    const float4 b4 = *(const float4*)&bias[lane * 4];

    #pragma unroll 1
    for (int row = wid; row < A_N; row += nw) {
        const float* fr = fatoms + (size_t)row * ATOM_FDIM;
        float ax = b4.x, ay = b4.y, az = b4.z, aw = b4.w;
        #pragma unroll
        for (int k = 0; k < ATOM_FDIM; ++k) {
            const float f = fr[k];
            ax += f * w[k].x; ay += f * w[k].y;
            az += f * w[k].z; aw += f * w[k].w;
        }
        ushort4 o;
        o.x = f2b(ax); o.y = f2b(ay); o.z = f2b(az); o.w = f2b(aw);
        *(ushort4*)(g_Fh + (size_t)row * HD + lane * 4) = o;
    }
}

// ------- K5: out[mol] = mean_a relu(Fh[a] + sum_j Q[agraph[a][j]]) -------
// R20 shape (kept; unmeasured in R20 due to k_inF blowup): ONE block per
// molecule, 512 threads; 32 threads own a FULL 512B Q-row per atom (16 atom
// groups, stride 16) -> one fetch per gathered row, max line utilization + L2
// reuse (R19's quarter-split hit the zero-reuse FETCH bound of 525 MB).
__global__ __launch_bounds__(512)
void k_gatherA(const int* __restrict__ agraph, float* __restrict__ out)
{
    const int mol = blockIdx.x;
    const int tid = threadIdx.x;                 // 0..511
    const int grp = tid >> 5;                    // 16 groups of 32 threads
    const int lc  = (tid & 31) * 8;              // col [0,256)

    const int s0 = g_mstart[mol];
    const int s1 = g_mstart[mol + 1];

    float s[8] = {0.f,0.f,0.f,0.f,0.f,0.f,0.f,0.f};
    #pragma unroll 1
    for (int a = s0 + grp; a < s1; a += 16) {
        const int* ap = agraph + (size_t)a * MAX_NB;
        int idx[MAX_NB];
        #pragma unroll
        for (int j = 0; j < MAX_NB; ++j) idx[j] = ap[j];
        const uint4 fv = *(const uint4*)(g_Fh + (size_t)a * HD + lc);
        float g0=0.f,g1=0.f,g2=0.f,g3=0.f,g4=0.f,g5=0.f,g6=0.f,g7=0.f;
        #pragma unroll
        for (int j = 0; j < MAX_NB; ++j) {
            const uint4 v = *(const uint4*)(g_Q + (size_t)idx[j] * HD + lc);
            g0 += blo(v.x); g1 += bhi(v.x);
            g2 += blo(v.y); g3 += bhi(v.y);
            g4 += blo(v.z); g5 += bhi(v.z);
            g6 += blo(v.w); g7 += bhi(v.w);
        }
        s[0] += fmaxf(g0 + blo(fv.x), 0.f); s[1] += fmaxf(g1 + bhi(fv.x), 0.f);
        s[2] += fmaxf(g2 + blo(fv.y), 0.f); s[3] += fmaxf(g3 + bhi(fv.y), 0.f);
        s[4] += fmaxf(g4 + blo(fv.z), 0.f); s[5] += fmaxf(g5 + bhi(fv.z), 0.f);
        s[6] += fmaxf(g6 + blo(fv.w), 0.f); s[7] += fmaxf(g7 + bhi(fv.w), 0.f);
    }

    __shared__ float red[16][260];               // padded: ~16.6 KB
    #pragma unroll
    for (int q = 0; q < 8; ++q) red[grp][lc + q] = s[q];
    __syncthreads();
    if (tid < 256) {
        float acc = 0.f;
        #pragma unroll
        for (int g = 0; g < 16; ++g) acc += red[g][tid];
        const float inv = 1.0f / fmaxf((float)(s1 - s0), 1.0f);
        out[(size_t)mol * HD + tid] = acc * inv;
    }
}

// ---------------- launch ----------------
extern "C" void kernel_launch(void* const* d_in, const int* in_sizes, int n_in,
                              void* d_out, int out_size, void* d_ws, size_t ws_size,
                              hipStream_t stream)
{
    const float* fatoms = (const float*)d_in[0];
    const float* fbonds = (const float*)d_in[1];
    const int*   agraph = (const int*)d_in[2];
    const int*   bgraph = (const int*)d_in[3];
    const float* tmsg   = (const float*)d_in[4];
    const int*   scope  = (const int*)d_in[5];
    const float* W_i    = (const float*)d_in[6];
    const float* W_h    = (const float*)d_in[7];
    const float* W_o    = (const float*)d_in[8];
    const float* W_ob   = (const float*)d_in[9];
    float* out = (float*)d_out;

    (void)d_ws; (void)ws_size;

    k_setup<<<5040, 256, 0, stream>>>(tmsg, W_h, W_o, scope);
    k_in<<<512, 256, 0, stream>>>(fbonds, W_i);             // binH + msg0

    // iter 0: P = [tmsg; msg0] @ Wh; msg1 = relu(binH + gatherP)
    k_gemmMF<<<(POOL_N + 127) / 128, 256, 0, stream>>>(0, 0, POOL_N);
    k_gather<<<B_N / 8, 256, 0, stream>>>(bgraph, 1);
    // iter 1: only msg rows of P change
    k_gemmMF<<<(B_N + 127) / 128, 256, 0, stream>>>(1, M_N, POOL_N);
    k_gather<<<B_N / 8, 256, 0, stream>>>(bgraph, 0);

    // readout: Q = [tmsg; msg0] @ Wo[35:291]; Fh = fatoms@Wo[0:35]+b; gather+mean
    k_gemmMF<<<(POOL_N + 127) / 128, 256, 0, stream>>>(2, 0, POOL_N);
    k_F<<<512, 256, 0, stream>>>(fatoms, W_o, W_ob);
    k_gatherA<<<N_MOLS, 512, 0, stream>>>(agraph, out);
}